// Round 5
// baseline (321.595 us; speedup 1.0000x reference)
//
#include <hip/hip_runtime.h>

// ImplicitNet fused MLP, bf16 MFMA, D = W·X^T, IN-PLACE LDS, 4-wave blocks.
// 256 threads/block (4 waves), 64 points/block, wave owns 64 output features
// (acc[4][4] = 64 f32). Halves LDS re-read traffic vs 8-wave/N=32 (R4's top pipe:
// each wave re-reads the whole 64x256 tile per layer; traffic ~ waves/block).
// Single 32KB activation buffer, overwritten in place (acc in regs across bar).
// Softplus+bf16-pack computed BEFORE the barrier; only LDS stores after it.
// 1/sqrt2 skip scale folded into W4 at prep (exact: (x*s)@W^T = x@(W*s)^T).
//
// d_ws: bf16 weights, fragment-major: chunk(ntile,ktile,lane) holds
// W[ntile*16 + (lane&15)][ktile*32 + (lane>>4)*8 + j]. MFMA A-operand.
// Padding: L0 K 51->64, L3 N 253->256, L8 N 257->272. ws >= 1,089,536 B.

typedef __attribute__((ext_vector_type(8))) short bf16x8;
typedef __attribute__((ext_vector_type(4))) float f32x4;
typedef __attribute__((ext_vector_type(2))) float f32x2;

#define PPTS 50000

__device__ __forceinline__ short f2bf(float f) {
    union { float f; unsigned u; } v; v.f = f;
    unsigned r = v.u + 0x7fffu + ((v.u >> 16) & 1u);   // RTNE (finite inputs)
    return (short)(r >> 16);
}

// packed f32x2 -> bf16x2 (RTNE), one VALU op (no builtin on gfx950 -> asm)
__device__ __forceinline__ unsigned cvt_pk_bf16(float lo, float hi) {
    unsigned r;
    asm("v_cvt_pk_bf16_f32 %0, %1, %2" : "=v"(r) : "v"(lo), "v"(hi));
    return r;
}

// softplus(100x)/100 on a pair = max(x,0) + ln(1+e)/100, e = exp(-100|x|).
// ln(1+e)/100 ~= e*(A + B*e + C*e^2); |err| <= 2.5e-5, exact as e->0.
// f32x2 ops lower to v_pk_{mul,fma,max}_f32 (one VALU op per pair).
__device__ __forceinline__ f32x2 sp100_pair(f32x2 y) {
    const f32x2 A2 = {6.9314718e-3f, 6.9314718e-3f};
    const f32x2 B2 = {-3.11522e-3f, -3.11522e-3f};
    const f32x2 C2 = {9.8829e-4f,  9.8829e-4f};
    const f32x2 K2 = {-144.26950408889634f, -144.26950408889634f};
    const f32x2 Z2 = {0.0f, 0.0f};
    f32x2 m = __builtin_elementwise_abs(y) * K2;
    f32x2 e = {__builtin_amdgcn_exp2f(m.x), __builtin_amdgcn_exp2f(m.y)};
    f32x2 t = __builtin_elementwise_fma(C2, e, B2);
    t = __builtin_elementwise_fma(t, e, A2);
    return __builtin_elementwise_fma(e, t, __builtin_elementwise_max(y, Z2));
}

// LDS tile [64][256] bf16, row stride 512B.
// Swizzle: byte ^= ((row&7) ^ 5*bit3(row)) << 4 — bijective within the row,
// multiple of 16 -> preserves 8/16B alignment.
__device__ __forceinline__ int xswz(int row) {
    return (((row & 7) ^ (5 * ((row >> 3) & 1))) << 4);
}
__device__ __forceinline__ short* xaddr(short* base, int row, int col) {
    int off = ((row << 9) + (col << 1)) ^ xswz(row);
    return (short*)((char*)base + off);
}
__device__ __forceinline__ const short* xaddrc(const short* base, int row, int col) {
    int off = ((row << 9) + (col << 1)) ^ xswz(row);
    return (const short*)((const char*)base + off);
}

// ---------------- weight prep: f32 row-major -> bf16 fragment-major ----------------
// W4 is pre-scaled by 1/sqrt2 (absorbs the reference's skip-concat scaling).
__global__ void prep_kernel(
    const float* __restrict__ W0, const float* __restrict__ W1, const float* __restrict__ W2,
    const float* __restrict__ W3, const float* __restrict__ W4, const float* __restrict__ W5,
    const float* __restrict__ W6, const float* __restrict__ W7, const float* __restrict__ W8,
    short* __restrict__ wbf)
{
    const int gid = blockIdx.x * blockDim.x + threadIdx.x;
    if (gid >= 68096) return;                       // total 16B chunks
    int l, cid; const float* Wsrc;
    if      (gid <  2048) { l = 0; cid = gid;         Wsrc = W0; }
    else if (gid < 10240) { l = 1; cid = gid -  2048; Wsrc = W1; }
    else if (gid < 18432) { l = 2; cid = gid - 10240; Wsrc = W2; }
    else if (gid < 26624) { l = 3; cid = gid - 18432; Wsrc = W3; }
    else if (gid < 34816) { l = 4; cid = gid - 26624; Wsrc = W4; }
    else if (gid < 43008) { l = 5; cid = gid - 34816; Wsrc = W5; }
    else if (gid < 51200) { l = 6; cid = gid - 43008; Wsrc = W6; }
    else if (gid < 59392) { l = 7; cid = gid - 51200; Wsrc = W7; }
    else                  { l = 8; cid = gid - 59392; Wsrc = W8; }
    const int NR   = (l == 3) ? 253 : ((l == 8) ? 257 : 256);
    const int KR   = (l == 0) ? 51 : 256;
    const int klog = (l == 0) ? 1 : 3;              // ktiles = Kpad/32 = 2 or 8
    const float sc = (l == 4) ? 0.70710678f : 1.0f; // fold skip 1/sqrt2 into W4
    const int lane  = cid & 63;
    const int tile  = cid >> 6;
    const int ntile = tile >> klog;
    const int ktile = tile & ((1 << klog) - 1);
    const int n  = ntile * 16 + (lane & 15);
    const int k0 = ktile * 32 + ((lane >> 4) << 3);
    bf16x8 v;
#pragma unroll
    for (int j = 0; j < 8; ++j) {
        int k = k0 + j;
        float f = (n < NR && k < KR) ? Wsrc[n * KR + k] * sc : 0.0f;
        v[j] = f2bf(f);
    }
    ((bf16x8*)wbf)[gid] = v;
}

// ------- one hidden layer, IN PLACE: acc = W @ xb^T; softplus in regs; bar; write --
// MODE 0: normal. MODE 1: layer 3 (N=253: mask cols 253..255).
template<int KSTEPS, int MODE>
__device__ __forceinline__ void layer_fwd(short* xb,
    const bf16x8* __restrict__ wl, const float* __restrict__ bias, int lane, int wid)
{
    const int prow = lane & 15;
    const int kg   = (lane >> 4) << 3;
    const int rb4  = (lane >> 4) << 2;
    f32x4 acc[4][4] = {};
#pragma unroll 2
    for (int ks = 0; ks < KSTEPS; ++ks) {
        bf16x8 a[4], b[4];
#pragma unroll
        for (int nii = 0; nii < 4; ++nii)
            a[nii] = wl[((wid * 4 + nii) * KSTEPS + ks) * 64 + lane];
#pragma unroll
        for (int mi = 0; mi < 4; ++mi)
            b[mi] = *(const bf16x8*)xaddrc(xb, mi * 16 + prow, ks * 32 + kg);
#pragma unroll
        for (int mi = 0; mi < 4; ++mi)
#pragma unroll
            for (int nii = 0; nii < 4; ++nii)
                acc[mi][nii] = __builtin_amdgcn_mfma_f32_16x16x32_bf16(
                    a[nii], b[mi], acc[mi][nii], 0, 0, 0);
    }
    // activation + bf16 pack entirely in registers (before the barrier)
    uint2 pk[4][4];
#pragma unroll
    for (int nii = 0; nii < 4; ++nii) {
        const int cb = (wid * 4 + nii) * 16 + rb4;
        f32x4 bv;
        if (MODE == 1 && cb == 252) { f32x4 tb = {bias[252], 0.f, 0.f, 0.f}; bv = tb; }
        else bv = *(const f32x4*)(bias + cb);
#pragma unroll
        for (int mi = 0; mi < 4; ++mi) {
            f32x2 y0 = {acc[mi][nii][0] + bv[0], acc[mi][nii][1] + bv[1]};
            f32x2 y1 = {acc[mi][nii][2] + bv[2], acc[mi][nii][3] + bv[3]};
            f32x2 r0 = sp100_pair(y0);
            f32x2 r1 = sp100_pair(y1);
            pk[nii][mi].x = cvt_pk_bf16(r0.x, r0.y);
            pk[nii][mi].y = cvt_pk_bf16(r1.x, r1.y);
        }
    }
    __syncthreads();                                  // all reads of xb complete
#pragma unroll
    for (int nii = 0; nii < 4; ++nii) {
        const int cb = (wid * 4 + nii) * 16 + rb4;
#pragma unroll
        for (int mi = 0; mi < 4; ++mi) {
            if (MODE == 1 && cb == 252)
                *xaddr(xb, mi * 16 + prow, 252) = (short)(pk[nii][mi].x & 0xffff);
            else
                *(uint2*)xaddr(xb, mi * 16 + prow, cb) = pk[nii][mi];
        }
    }
}

// ---------------- fused network kernel: 64 points, 4 waves, 32 KB LDS --------------
__global__ __launch_bounds__(256, 4) void net_kernel(
    const float* __restrict__ xin, const float* __restrict__ cond,
    const bf16x8* __restrict__ W,
    const float* __restrict__ b0, const float* __restrict__ b1, const float* __restrict__ b2,
    const float* __restrict__ b3, const float* __restrict__ b4, const float* __restrict__ b5,
    const float* __restrict__ b6, const float* __restrict__ b7, const float* __restrict__ b8,
    float* __restrict__ out)
{
    __shared__ short xb[64 * 256];
    const int t    = threadIdx.x;
    const int pt0  = blockIdx.x * 64;
    const int lane = t & 63;
    const int wid  = t >> 6;      // 0..3

    // hoist skip-connection values (wave 0 holds them; written after layer 3).
    // Unscaled: the 1/sqrt2 is folded into W4.
    float sk[3] = {0.f, 0.f, 0.f};
    if (t < 64) {
#pragma unroll
        for (int c = 0; c < 3; ++c)
            sk[c] = xin[(pt0 + t) * 3 + c];
    }

    // build X0 = [x(3) | cond(48) | zeros(..63)] per point, bf16 into LDS cols 0..63
    {
        const int row   = t >> 2;           // 0..63
        const int c0    = (t & 3) << 4;     // 0,16,32,48
        const int point = pt0 + row;
        const int batch = point / PPTS;
        const float* xp = xin + point * 3;
        const float* cp = cond + batch * 48;
#pragma unroll
        for (int h = 0; h < 2; ++h) {
            bf16x8 v;
#pragma unroll
            for (int i = 0; i < 8; ++i) {
                int c = c0 + h * 8 + i;
                float f = (c < 3) ? xp[c] : ((c < 51) ? cp[c - 3] : 0.0f);
                v[i] = f2bf(f);
            }
            *(bf16x8*)xaddr(xb, row, c0 + h * 8) = v;
        }
    }
    __syncthreads();

    layer_fwd<2, 0>(xb, W +     0, b0, lane, wid); __syncthreads();
    layer_fwd<8, 0>(xb, W +  2048, b1, lane, wid); __syncthreads();
    layer_fwd<8, 0>(xb, W + 10240, b2, lane, wid); __syncthreads();
    layer_fwd<8, 1>(xb, W + 18432, b3, lane, wid);
    // skip connection: cols 253..255 of layer-4 input = x_in (scale is in W4)
    if (t < 64) {
#pragma unroll
        for (int c = 0; c < 3; ++c)
            *xaddr(xb, t, 253 + c) = f2bf(sk[c]);
    }
    __syncthreads();
    layer_fwd<8, 0>(xb, W + 26624, b4, lane, wid); __syncthreads();
    layer_fwd<8, 0>(xb, W + 34816, b5, lane, wid); __syncthreads();
    layer_fwd<8, 0>(xb, W + 43008, b6, lane, wid); __syncthreads();
    layer_fwd<8, 0>(xb, W + 51200, b7, lane, wid); __syncthreads();

    // layer 8: N=257 (17 n-tiles), no activation, f32 store to d_out.
    // Two m-halves (32 points each) to keep live accumulators small;
    // wave 0 carries n-tile 16 (only col 256 real).
    {
        const bf16x8* wl = W + 59392;
        const int prow = lane & 15;
        const int kg   = (lane >> 4) << 3;
        const int rb4  = (lane >> 4) << 2;
#pragma unroll
        for (int half = 0; half < 2; ++half) {
            f32x4 acc[2][4] = {};
            f32x4 acc2[2]   = {};
#pragma unroll 2
            for (int ks = 0; ks < 8; ++ks) {
                bf16x8 a[4], b[2], a2;
#pragma unroll
                for (int nii = 0; nii < 4; ++nii)
                    a[nii] = wl[((wid * 4 + nii) * 8 + ks) * 64 + lane];
                if (wid == 0) a2 = wl[(128 + ks) * 64 + lane];
#pragma unroll
                for (int m2 = 0; m2 < 2; ++m2)
                    b[m2] = *(const bf16x8*)xaddrc(xb, (half * 2 + m2) * 16 + prow,
                                                   ks * 32 + kg);
#pragma unroll
                for (int m2 = 0; m2 < 2; ++m2)
#pragma unroll
                    for (int nii = 0; nii < 4; ++nii)
                        acc[m2][nii] = __builtin_amdgcn_mfma_f32_16x16x32_bf16(
                            a[nii], b[m2], acc[m2][nii], 0, 0, 0);
                if (wid == 0) {
#pragma unroll
                    for (int m2 = 0; m2 < 2; ++m2)
                        acc2[m2] = __builtin_amdgcn_mfma_f32_16x16x32_bf16(
                            a2, b[m2], acc2[m2], 0, 0, 0);
                }
            }
#pragma unroll
            for (int nii = 0; nii < 4; ++nii) {
                const int cb = (wid * 4 + nii) * 16 + rb4;          // <= 252
                const f32x4 bv = *(const f32x4*)(b8 + cb);
#pragma unroll
                for (int m2 = 0; m2 < 2; ++m2) {
                    const int rowoff = (pt0 + (half * 2 + m2) * 16 + prow) * 257 + cb;
#pragma unroll
                    for (int r = 0; r < 4; ++r)
                        out[rowoff + r] = acc[m2][nii][r] + bv[r];
                }
            }
            if (wid == 0 && rb4 == 0) {                              // lanes 0..15
                const float blast = b8[256];
#pragma unroll
                for (int m2 = 0; m2 < 2; ++m2)
                    out[(pt0 + (half * 2 + m2) * 16 + prow) * 257 + 256]
                        = acc2[m2][0] + blast;
            }
        }
    }
}

extern "C" void kernel_launch(void* const* d_in, const int* in_sizes, int n_in,
                              void* d_out, int out_size, void* d_ws, size_t ws_size,
                              hipStream_t stream)
{
    const float* xin  = (const float*)d_in[0];
    const float* cond = (const float*)d_in[1];
    const float* Wp[9]; const float* bp[9];
    for (int l = 0; l < 9; ++l) { Wp[l] = (const float*)d_in[2 + 2 * l]; bp[l] = (const float*)d_in[3 + 2 * l]; }
    short* wbf = (short*)d_ws;   // needs 1,089,536 B

    prep_kernel<<<dim3(266), dim3(256), 0, stream>>>(
        Wp[0], Wp[1], Wp[2], Wp[3], Wp[4], Wp[5], Wp[6], Wp[7], Wp[8], wbf);
    net_kernel<<<dim3(3125), dim3(256), 0, stream>>>(
        xin, cond, (const bf16x8*)wbf,
        bp[0], bp[1], bp[2], bp[3], bp[4], bp[5], bp[6], bp[7], bp[8],
        (float*)d_out);
}

// Round 6
// 319.124 us; speedup vs baseline: 1.0077x; 1.0077x over previous
//
#include <hip/hip_runtime.h>

// ImplicitNet fused MLP, bf16 MFMA, D = W·X^T, IN-PLACE LDS, 4-wave blocks.
// 256 threads/block (4 waves), 64 points/block, wave owns 64 output features
// (acc[4][4] = 64 f32 in the unified VGPR/AGPR file).
// R6 register diet vs R5: (a) bias folded into accumulator INIT (MFMA C-in),
// (b) softplus applied IN PLACE on acc pre-barrier (no pk[] array live across
// the barrier). Target: total regs <= 128 -> 4 blocks/CU with launch_bounds(256,4).
//
// d_ws: bf16 weights, fragment-major: chunk(ntile,ktile,lane) holds
// W[ntile*16 + (lane&15)][ktile*32 + (lane>>4)*8 + j]. MFMA A-operand.
// W4 pre-scaled by 1/sqrt2 (absorbs skip-concat scale; exact linearity).
// Padding: L0 K 51->64, L3 N 253->256, L8 N 257->272. ws >= 1,089,536 B.

typedef __attribute__((ext_vector_type(8))) short bf16x8;
typedef __attribute__((ext_vector_type(4))) float f32x4;
typedef __attribute__((ext_vector_type(2))) float f32x2;

#define PPTS 50000

__device__ __forceinline__ short f2bf(float f) {
    union { float f; unsigned u; } v; v.f = f;
    unsigned r = v.u + 0x7fffu + ((v.u >> 16) & 1u);   // RTNE (finite inputs)
    return (short)(r >> 16);
}

// packed f32x2 -> bf16x2 (RTNE), one VALU op (no builtin on gfx950 -> asm)
__device__ __forceinline__ unsigned cvt_pk_bf16(float lo, float hi) {
    unsigned r;
    asm("v_cvt_pk_bf16_f32 %0, %1, %2" : "=v"(r) : "v"(lo), "v"(hi));
    return r;
}

// softplus(100x)/100 on a pair = max(x,0) + ln(1+e)/100, e = exp(-100|x|).
// ln(1+e)/100 ~= e*(A + B*e + C*e^2); |err| <= 2.5e-5, exact as e->0.
// f32x2 ops lower to v_pk_{mul,fma,max}_f32 (one VALU op per pair).
__device__ __forceinline__ f32x2 sp100_pair(f32x2 y) {
    const f32x2 A2 = {6.9314718e-3f, 6.9314718e-3f};
    const f32x2 B2 = {-3.11522e-3f, -3.11522e-3f};
    const f32x2 C2 = {9.8829e-4f,  9.8829e-4f};
    const f32x2 K2 = {-144.26950408889634f, -144.26950408889634f};
    const f32x2 Z2 = {0.0f, 0.0f};
    f32x2 m = __builtin_elementwise_abs(y) * K2;
    f32x2 e = {__builtin_amdgcn_exp2f(m.x), __builtin_amdgcn_exp2f(m.y)};
    f32x2 t = __builtin_elementwise_fma(C2, e, B2);
    t = __builtin_elementwise_fma(t, e, A2);
    return __builtin_elementwise_fma(e, t, __builtin_elementwise_max(y, Z2));
}

// LDS tile [64][256] bf16, row stride 512B.
// Swizzle: byte ^= ((row&7) ^ 5*bit3(row)) << 4 — bijective within the row,
// multiple of 16 -> preserves 8/16B alignment.
__device__ __forceinline__ int xswz(int row) {
    return (((row & 7) ^ (5 * ((row >> 3) & 1))) << 4);
}
__device__ __forceinline__ short* xaddr(short* base, int row, int col) {
    int off = ((row << 9) + (col << 1)) ^ xswz(row);
    return (short*)((char*)base + off);
}
__device__ __forceinline__ const short* xaddrc(const short* base, int row, int col) {
    int off = ((row << 9) + (col << 1)) ^ xswz(row);
    return (const short*)((const char*)base + off);
}

// ---------------- weight prep: f32 row-major -> bf16 fragment-major ----------------
// W4 is pre-scaled by 1/sqrt2 (absorbs the reference's skip-concat scaling).
__global__ void prep_kernel(
    const float* __restrict__ W0, const float* __restrict__ W1, const float* __restrict__ W2,
    const float* __restrict__ W3, const float* __restrict__ W4, const float* __restrict__ W5,
    const float* __restrict__ W6, const float* __restrict__ W7, const float* __restrict__ W8,
    short* __restrict__ wbf)
{
    const int gid = blockIdx.x * blockDim.x + threadIdx.x;
    if (gid >= 68096) return;                       // total 16B chunks
    int l, cid; const float* Wsrc;
    if      (gid <  2048) { l = 0; cid = gid;         Wsrc = W0; }
    else if (gid < 10240) { l = 1; cid = gid -  2048; Wsrc = W1; }
    else if (gid < 18432) { l = 2; cid = gid - 10240; Wsrc = W2; }
    else if (gid < 26624) { l = 3; cid = gid - 18432; Wsrc = W3; }
    else if (gid < 34816) { l = 4; cid = gid - 26624; Wsrc = W4; }
    else if (gid < 43008) { l = 5; cid = gid - 34816; Wsrc = W5; }
    else if (gid < 51200) { l = 6; cid = gid - 43008; Wsrc = W6; }
    else if (gid < 59392) { l = 7; cid = gid - 51200; Wsrc = W7; }
    else                  { l = 8; cid = gid - 59392; Wsrc = W8; }
    const int NR   = (l == 3) ? 253 : ((l == 8) ? 257 : 256);
    const int KR   = (l == 0) ? 51 : 256;
    const int klog = (l == 0) ? 1 : 3;              // ktiles = Kpad/32 = 2 or 8
    const float sc = (l == 4) ? 0.70710678f : 1.0f; // fold skip 1/sqrt2 into W4
    const int lane  = cid & 63;
    const int tile  = cid >> 6;
    const int ntile = tile >> klog;
    const int ktile = tile & ((1 << klog) - 1);
    const int n  = ntile * 16 + (lane & 15);
    const int k0 = ktile * 32 + ((lane >> 4) << 3);
    bf16x8 v;
#pragma unroll
    for (int j = 0; j < 8; ++j) {
        int k = k0 + j;
        float f = (n < NR && k < KR) ? Wsrc[n * KR + k] * sc : 0.0f;
        v[j] = f2bf(f);
    }
    ((bf16x8*)wbf)[gid] = v;
}

// ------- one hidden layer, IN PLACE: acc = bias; acc += W @ xb^T; softplus(acc);
//         barrier; bf16-pack + write. MODE 0: normal. MODE 1: L3 (mask 253..255).
template<int KSTEPS, int MODE>
__device__ __forceinline__ void layer_fwd(short* xb,
    const bf16x8* __restrict__ wl, const float* __restrict__ bias, int lane, int wid)
{
    const int prow = lane & 15;
    const int kg   = (lane >> 4) << 3;
    const int rb4  = (lane >> 4) << 2;
    // init accumulators with the bias fragment (MFMA C-in carries the bias; the
    // feature index (wid*4+nii)*16 + rb4 + r is mi-independent -> broadcast).
    f32x4 acc[4][4];
#pragma unroll
    for (int nii = 0; nii < 4; ++nii) {
        const int cb = (wid * 4 + nii) * 16 + rb4;
        f32x4 bv;
        if (MODE == 1 && cb == 252) { f32x4 tb = {bias[252], 0.f, 0.f, 0.f}; bv = tb; }
        else bv = *(const f32x4*)(bias + cb);
#pragma unroll
        for (int mi = 0; mi < 4; ++mi)
            acc[mi][nii] = bv;
    }
#pragma unroll 2
    for (int ks = 0; ks < KSTEPS; ++ks) {
        bf16x8 a[4], b[4];
#pragma unroll
        for (int nii = 0; nii < 4; ++nii)
            a[nii] = wl[((wid * 4 + nii) * KSTEPS + ks) * 64 + lane];
#pragma unroll
        for (int mi = 0; mi < 4; ++mi)
            b[mi] = *(const bf16x8*)xaddrc(xb, mi * 16 + prow, ks * 32 + kg);
#pragma unroll
        for (int mi = 0; mi < 4; ++mi)
#pragma unroll
            for (int nii = 0; nii < 4; ++nii)
                acc[mi][nii] = __builtin_amdgcn_mfma_f32_16x16x32_bf16(
                    a[nii], b[mi], acc[mi][nii], 0, 0, 0);
    }
    // softplus IN PLACE on acc (no extra live registers across the barrier)
#pragma unroll
    for (int nii = 0; nii < 4; ++nii)
#pragma unroll
        for (int mi = 0; mi < 4; ++mi) {
            f32x2 y0 = {acc[mi][nii][0], acc[mi][nii][1]};
            f32x2 y1 = {acc[mi][nii][2], acc[mi][nii][3]};
            f32x2 r0 = sp100_pair(y0);
            f32x2 r1 = sp100_pair(y1);
            acc[mi][nii][0] = r0.x; acc[mi][nii][1] = r0.y;
            acc[mi][nii][2] = r1.x; acc[mi][nii][3] = r1.y;
        }
    __syncthreads();                                  // all reads of xb complete
#pragma unroll
    for (int nii = 0; nii < 4; ++nii) {
        const int cb = (wid * 4 + nii) * 16 + rb4;
#pragma unroll
        for (int mi = 0; mi < 4; ++mi) {
            unsigned p01 = cvt_pk_bf16(acc[mi][nii][0], acc[mi][nii][1]);
            unsigned p23 = cvt_pk_bf16(acc[mi][nii][2], acc[mi][nii][3]);
            if (MODE == 1 && cb == 252) {
                *xaddr(xb, mi * 16 + prow, 252) = (short)(p01 & 0xffff);
            } else {
                uint2 pk; pk.x = p01; pk.y = p23;
                *(uint2*)xaddr(xb, mi * 16 + prow, cb) = pk;
            }
        }
    }
}

// ---------------- fused network kernel: 64 points, 4 waves, 32 KB LDS --------------
__global__ __launch_bounds__(256, 4) void net_kernel(
    const float* __restrict__ xin, const float* __restrict__ cond,
    const bf16x8* __restrict__ W,
    const float* __restrict__ b0, const float* __restrict__ b1, const float* __restrict__ b2,
    const float* __restrict__ b3, const float* __restrict__ b4, const float* __restrict__ b5,
    const float* __restrict__ b6, const float* __restrict__ b7, const float* __restrict__ b8,
    float* __restrict__ out)
{
    __shared__ short xb[64 * 256];
    const int t    = threadIdx.x;
    const int pt0  = blockIdx.x * 64;
    const int lane = t & 63;
    const int wid  = t >> 6;      // 0..3

    // hoist skip-connection values (written after layer 3; scale folded into W4)
    float sk[3] = {0.f, 0.f, 0.f};
    if (t < 64) {
#pragma unroll
        for (int c = 0; c < 3; ++c)
            sk[c] = xin[(pt0 + t) * 3 + c];
    }

    // build X0 = [x(3) | cond(48) | zeros(..63)] per point, bf16 into LDS cols 0..63
    {
        const int row   = t >> 2;           // 0..63
        const int c0    = (t & 3) << 4;     // 0,16,32,48
        const int point = pt0 + row;
        const int batch = point / PPTS;
        const float* xp = xin + point * 3;
        const float* cp = cond + batch * 48;
#pragma unroll
        for (int h = 0; h < 2; ++h) {
            bf16x8 v;
#pragma unroll
            for (int i = 0; i < 8; ++i) {
                int c = c0 + h * 8 + i;
                float f = (c < 3) ? xp[c] : ((c < 51) ? cp[c - 3] : 0.0f);
                v[i] = f2bf(f);
            }
            *(bf16x8*)xaddr(xb, row, c0 + h * 8) = v;
        }
    }
    __syncthreads();

    layer_fwd<2, 0>(xb, W +     0, b0, lane, wid); __syncthreads();
    layer_fwd<8, 0>(xb, W +  2048, b1, lane, wid); __syncthreads();
    layer_fwd<8, 0>(xb, W + 10240, b2, lane, wid); __syncthreads();
    layer_fwd<8, 1>(xb, W + 18432, b3, lane, wid);
    // skip connection: cols 253..255 of layer-4 input = x_in (scale is in W4)
    if (t < 64) {
#pragma unroll
        for (int c = 0; c < 3; ++c)
            *xaddr(xb, t, 253 + c) = f2bf(sk[c]);
    }
    __syncthreads();
    layer_fwd<8, 0>(xb, W + 26624, b4, lane, wid); __syncthreads();
    layer_fwd<8, 0>(xb, W + 34816, b5, lane, wid); __syncthreads();
    layer_fwd<8, 0>(xb, W + 43008, b6, lane, wid); __syncthreads();
    layer_fwd<8, 0>(xb, W + 51200, b7, lane, wid); __syncthreads();

    // layer 8: N=257 (17 n-tiles), no activation, bias in acc-init, f32 store.
    // Two m-halves (32 points each) to keep live accumulators small;
    // wave 0 carries n-tile 16 (only col 256 real).
    {
        const bf16x8* wl = W + 59392;
        const int prow = lane & 15;
        const int kg   = (lane >> 4) << 3;
        const int rb4  = (lane >> 4) << 2;
        const float blast = b8[256];
#pragma unroll
        for (int half = 0; half < 2; ++half) {
            f32x4 acc[2][4];
            f32x4 acc2[2];
#pragma unroll
            for (int nii = 0; nii < 4; ++nii) {
                const int cb = (wid * 4 + nii) * 16 + rb4;          // <= 252
                const f32x4 bv = *(const f32x4*)(b8 + cb);
#pragma unroll
                for (int m2 = 0; m2 < 2; ++m2)
                    acc[m2][nii] = bv;
            }
            {
                f32x4 bz = {(rb4 == 0) ? blast : 0.f, 0.f, 0.f, 0.f};
                acc2[0] = bz; acc2[1] = bz;
            }
#pragma unroll 2
            for (int ks = 0; ks < 8; ++ks) {
                bf16x8 a[4], b[2], a2;
#pragma unroll
                for (int nii = 0; nii < 4; ++nii)
                    a[nii] = wl[((wid * 4 + nii) * 8 + ks) * 64 + lane];
                if (wid == 0) a2 = wl[(128 + ks) * 64 + lane];
#pragma unroll
                for (int m2 = 0; m2 < 2; ++m2)
                    b[m2] = *(const bf16x8*)xaddrc(xb, (half * 2 + m2) * 16 + prow,
                                                   ks * 32 + kg);
#pragma unroll
                for (int m2 = 0; m2 < 2; ++m2)
#pragma unroll
                    for (int nii = 0; nii < 4; ++nii)
                        acc[m2][nii] = __builtin_amdgcn_mfma_f32_16x16x32_bf16(
                            a[nii], b[m2], acc[m2][nii], 0, 0, 0);
                if (wid == 0) {
#pragma unroll
                    for (int m2 = 0; m2 < 2; ++m2)
                        acc2[m2] = __builtin_amdgcn_mfma_f32_16x16x32_bf16(
                            a2, b[m2], acc2[m2], 0, 0, 0);
                }
            }
#pragma unroll
            for (int nii = 0; nii < 4; ++nii) {
                const int cb = (wid * 4 + nii) * 16 + rb4;          // <= 252
#pragma unroll
                for (int m2 = 0; m2 < 2; ++m2) {
                    const int rowoff = (pt0 + (half * 2 + m2) * 16 + prow) * 257 + cb;
#pragma unroll
                    for (int r = 0; r < 4; ++r)
                        out[rowoff + r] = acc[m2][nii][r];
                }
            }
            if (wid == 0 && rb4 == 0) {                              // lanes 0..15
#pragma unroll
                for (int m2 = 0; m2 < 2; ++m2)
                    out[(pt0 + (half * 2 + m2) * 16 + prow) * 257 + 256]
                        = acc2[m2][0];
            }
        }
    }
}

extern "C" void kernel_launch(void* const* d_in, const int* in_sizes, int n_in,
                              void* d_out, int out_size, void* d_ws, size_t ws_size,
                              hipStream_t stream)
{
    const float* xin  = (const float*)d_in[0];
    const float* cond = (const float*)d_in[1];
    const float* Wp[9]; const float* bp[9];
    for (int l = 0; l < 9; ++l) { Wp[l] = (const float*)d_in[2 + 2 * l]; bp[l] = (const float*)d_in[3 + 2 * l]; }
    short* wbf = (short*)d_ws;   // needs 1,089,536 B

    prep_kernel<<<dim3(266), dim3(256), 0, stream>>>(
        Wp[0], Wp[1], Wp[2], Wp[3], Wp[4], Wp[5], Wp[6], Wp[7], Wp[8], wbf);
    net_kernel<<<dim3(3125), dim3(256), 0, stream>>>(
        xin, cond, (const bf16x8*)wbf,
        bp[0], bp[1], bp[2], bp[3], bp[4], bp[5], bp[6], bp[7], bp[8],
        (float*)d_out);
}

// Round 7
// 303.003 us; speedup vs baseline: 1.0614x; 1.0532x over previous
//
#include <hip/hip_runtime.h>

// ImplicitNet fused MLP, bf16 MFMA, D = W·X^T, IN-PLACE LDS, 4-wave blocks.
// R7: (a) lgkmcnt-only barriers (global weight loads stay in flight across
// layer boundaries -- __syncthreads would drain vmcnt(0), exposing L2 latency
// every layer; this is the m97 barrier-drain stall), (b) cross-layer weight
// prefetch: ks=0 A-fragments of layer l+1 issued before layer l's barriers,
// (c) launch_bounds(256,3) to fit the +16 prefetch VGPRs without spill.
//
// d_ws: bf16 weights, fragment-major: chunk(ntile,ktile,lane) holds
// W[ntile*16 + (lane&15)][ktile*32 + (lane>>4)*8 + j]. MFMA A-operand.
// W4 pre-scaled by 1/sqrt2 (absorbs skip-concat scale; exact linearity).
// Padding: L0 K 51->64, L3 N 253->256, L8 N 257->272. ws >= 1,089,536 B.

typedef __attribute__((ext_vector_type(8))) short bf16x8;
typedef __attribute__((ext_vector_type(4))) float f32x4;
typedef __attribute__((ext_vector_type(2))) float f32x2;

#define PPTS 50000

__device__ __forceinline__ short f2bf(float f) {
    union { float f; unsigned u; } v; v.f = f;
    unsigned r = v.u + 0x7fffu + ((v.u >> 16) & 1u);   // RTNE (finite inputs)
    return (short)(r >> 16);
}

// packed f32x2 -> bf16x2 (RTNE), one VALU op (no builtin on gfx950 -> asm)
__device__ __forceinline__ unsigned cvt_pk_bf16(float lo, float hi) {
    unsigned r;
    asm("v_cvt_pk_bf16_f32 %0, %1, %2" : "=v"(r) : "v"(lo), "v"(hi));
    return r;
}

// Workgroup barrier that waits ONLY on LDS ops (lgkmcnt). Global loads in
// flight (weight prefetch) are NOT drained -- that's the point. LDS
// producer->consumer visibility within the CU is covered by lgkmcnt(0) +
// s_barrier. sched_barrier(0) pins compiler motion (guide rule #18).
__device__ __forceinline__ void bar_lgkm() {
    asm volatile("s_waitcnt lgkmcnt(0)" ::: "memory");
    __builtin_amdgcn_s_barrier();
    __builtin_amdgcn_sched_barrier(0);
}

// softplus(100x)/100 on a pair = max(x,0) + ln(1+e)/100, e = exp(-100|x|).
// ln(1+e)/100 ~= e*(A + B*e + C*e^2); |err| <= 2.5e-5, exact as e->0.
__device__ __forceinline__ f32x2 sp100_pair(f32x2 y) {
    const f32x2 A2 = {6.9314718e-3f, 6.9314718e-3f};
    const f32x2 B2 = {-3.11522e-3f, -3.11522e-3f};
    const f32x2 C2 = {9.8829e-4f,  9.8829e-4f};
    const f32x2 K2 = {-144.26950408889634f, -144.26950408889634f};
    const f32x2 Z2 = {0.0f, 0.0f};
    f32x2 m = __builtin_elementwise_abs(y) * K2;
    f32x2 e = {__builtin_amdgcn_exp2f(m.x), __builtin_amdgcn_exp2f(m.y)};
    f32x2 t = __builtin_elementwise_fma(C2, e, B2);
    t = __builtin_elementwise_fma(t, e, A2);
    return __builtin_elementwise_fma(e, t, __builtin_elementwise_max(y, Z2));
}

// LDS tile [64][256] bf16, row stride 512B.
// Swizzle: byte ^= ((row&7) ^ 5*bit3(row)) << 4 — bijective within the row,
// multiple of 16 -> preserves 8/16B alignment.
__device__ __forceinline__ int xswz(int row) {
    return (((row & 7) ^ (5 * ((row >> 3) & 1))) << 4);
}
__device__ __forceinline__ short* xaddr(short* base, int row, int col) {
    int off = ((row << 9) + (col << 1)) ^ xswz(row);
    return (short*)((char*)base + off);
}
__device__ __forceinline__ const short* xaddrc(const short* base, int row, int col) {
    int off = ((row << 9) + (col << 1)) ^ xswz(row);
    return (const short*)((const char*)base + off);
}

// ---------------- weight prep: f32 row-major -> bf16 fragment-major ----------------
__global__ void prep_kernel(
    const float* __restrict__ W0, const float* __restrict__ W1, const float* __restrict__ W2,
    const float* __restrict__ W3, const float* __restrict__ W4, const float* __restrict__ W5,
    const float* __restrict__ W6, const float* __restrict__ W7, const float* __restrict__ W8,
    short* __restrict__ wbf)
{
    const int gid = blockIdx.x * blockDim.x + threadIdx.x;
    if (gid >= 68096) return;                       // total 16B chunks
    int l, cid; const float* Wsrc;
    if      (gid <  2048) { l = 0; cid = gid;         Wsrc = W0; }
    else if (gid < 10240) { l = 1; cid = gid -  2048; Wsrc = W1; }
    else if (gid < 18432) { l = 2; cid = gid - 10240; Wsrc = W2; }
    else if (gid < 26624) { l = 3; cid = gid - 18432; Wsrc = W3; }
    else if (gid < 34816) { l = 4; cid = gid - 26624; Wsrc = W4; }
    else if (gid < 43008) { l = 5; cid = gid - 34816; Wsrc = W5; }
    else if (gid < 51200) { l = 6; cid = gid - 43008; Wsrc = W6; }
    else if (gid < 59392) { l = 7; cid = gid - 51200; Wsrc = W7; }
    else                  { l = 8; cid = gid - 59392; Wsrc = W8; }
    const int NR   = (l == 3) ? 253 : ((l == 8) ? 257 : 256);
    const int KR   = (l == 0) ? 51 : 256;
    const int klog = (l == 0) ? 1 : 3;              // ktiles = Kpad/32 = 2 or 8
    const float sc = (l == 4) ? 0.70710678f : 1.0f; // fold skip 1/sqrt2 into W4
    const int lane  = cid & 63;
    const int tile  = cid >> 6;
    const int ntile = tile >> klog;
    const int ktile = tile & ((1 << klog) - 1);
    const int n  = ntile * 16 + (lane & 15);
    const int k0 = ktile * 32 + ((lane >> 4) << 3);
    bf16x8 v;
#pragma unroll
    for (int j = 0; j < 8; ++j) {
        int k = k0 + j;
        float f = (n < NR && k < KR) ? Wsrc[n * KR + k] * sc : 0.0f;
        v[j] = f2bf(f);
    }
    ((bf16x8*)wbf)[gid] = v;
}

// ------- one hidden layer, IN PLACE, with cross-layer weight prefetch -------------
// apre (in): ks=0 A-frags of THIS layer, already in flight/registers.
// apre (out): ks=0 A-frags of NEXT layer (KSTEPS_next = 8 for all), issued here,
// consumed after two lgkm-only barriers (vmcnt stays live across them).
// MODE 0: normal. MODE 1: layer 3 (N=253: mask cols 253..255).
template<int KSTEPS, int MODE>
__device__ __forceinline__ void layer_fwd(short* xb,
    const bf16x8* __restrict__ wl, const bf16x8* __restrict__ wlnext,
    const float* __restrict__ bias, int lane, int wid, bf16x8 (&apre)[4])
{
    const int prow = lane & 15;
    const int kg   = (lane >> 4) << 3;
    const int rb4  = (lane >> 4) << 2;
    // bias folded into accumulator init (MFMA C-in); feature idx is mi-independent
    f32x4 acc[4][4];
#pragma unroll
    for (int nii = 0; nii < 4; ++nii) {
        const int cb = (wid * 4 + nii) * 16 + rb4;
        f32x4 bv;
        if (MODE == 1 && cb == 252) { f32x4 tb = {bias[252], 0.f, 0.f, 0.f}; bv = tb; }
        else bv = *(const f32x4*)(bias + cb);
#pragma unroll
        for (int mi = 0; mi < 4; ++mi)
            acc[mi][nii] = bv;
    }
#pragma unroll 2
    for (int ks = 0; ks < KSTEPS; ++ks) {
        bf16x8 a[4], b[4];
#pragma unroll
        for (int nii = 0; nii < 4; ++nii)
            a[nii] = (ks == 0) ? apre[nii]
                               : wl[((wid * 4 + nii) * KSTEPS + ks) * 64 + lane];
#pragma unroll
        for (int mi = 0; mi < 4; ++mi)
            b[mi] = *(const bf16x8*)xaddrc(xb, mi * 16 + prow, ks * 32 + kg);
#pragma unroll
        for (int mi = 0; mi < 4; ++mi)
#pragma unroll
            for (int nii = 0; nii < 4; ++nii)
                acc[mi][nii] = __builtin_amdgcn_mfma_f32_16x16x32_bf16(
                    a[nii], b[mi], acc[mi][nii], 0, 0, 0);
    }
    // prefetch next layer's ks=0 A-frags (KSTEPS_next == 8 for every next layer);
    // these global loads stay in flight across both lgkm-only barriers below.
#pragma unroll
    for (int nii = 0; nii < 4; ++nii)
        apre[nii] = wlnext[(wid * 4 + nii) * 512 + lane];
    // softplus IN PLACE on acc (register-only; before the read-barrier)
#pragma unroll
    for (int nii = 0; nii < 4; ++nii)
#pragma unroll
        for (int mi = 0; mi < 4; ++mi) {
            f32x2 y0 = {acc[mi][nii][0], acc[mi][nii][1]};
            f32x2 y1 = {acc[mi][nii][2], acc[mi][nii][3]};
            f32x2 r0 = sp100_pair(y0);
            f32x2 r1 = sp100_pair(y1);
            acc[mi][nii][0] = r0.x; acc[mi][nii][1] = r0.y;
            acc[mi][nii][2] = r1.x; acc[mi][nii][3] = r1.y;
        }
    bar_lgkm();                                       // all reads of xb complete
#pragma unroll
    for (int nii = 0; nii < 4; ++nii) {
        const int cb = (wid * 4 + nii) * 16 + rb4;
#pragma unroll
        for (int mi = 0; mi < 4; ++mi) {
            unsigned p01 = cvt_pk_bf16(acc[mi][nii][0], acc[mi][nii][1]);
            unsigned p23 = cvt_pk_bf16(acc[mi][nii][2], acc[mi][nii][3]);
            if (MODE == 1 && cb == 252) {
                *xaddr(xb, mi * 16 + prow, 252) = (short)(p01 & 0xffff);
            } else {
                uint2 pk; pk.x = p01; pk.y = p23;
                *(uint2*)xaddr(xb, mi * 16 + prow, cb) = pk;
            }
        }
    }
}

// ---------------- fused network kernel: 64 points, 4 waves, 32 KB LDS --------------
__global__ __launch_bounds__(256, 3) void net_kernel(
    const float* __restrict__ xin, const float* __restrict__ cond,
    const bf16x8* __restrict__ W,
    const float* __restrict__ b0, const float* __restrict__ b1, const float* __restrict__ b2,
    const float* __restrict__ b3, const float* __restrict__ b4, const float* __restrict__ b5,
    const float* __restrict__ b6, const float* __restrict__ b7, const float* __restrict__ b8,
    float* __restrict__ out)
{
    __shared__ short xb[64 * 256];
    const int t    = threadIdx.x;
    const int pt0  = blockIdx.x * 64;
    const int lane = t & 63;
    const int wid  = t >> 6;      // 0..3

    // prefetch layer-0 ks=0 A-frags FIRST (hides cold weight fetch under X0 build)
    bf16x8 apre[4];
#pragma unroll
    for (int nii = 0; nii < 4; ++nii)
        apre[nii] = W[(wid * 4 + nii) * 128 + lane];   // KSTEPS(L0)=2

    // hoist skip-connection values (written after layer 3; scale folded into W4)
    float sk[3] = {0.f, 0.f, 0.f};
    if (t < 64) {
#pragma unroll
        for (int c = 0; c < 3; ++c)
            sk[c] = xin[(pt0 + t) * 3 + c];
    }

    // build X0 = [x(3) | cond(48) | zeros(..63)] per point, bf16 into LDS cols 0..63
    {
        const int row   = t >> 2;           // 0..63
        const int c0    = (t & 3) << 4;     // 0,16,32,48
        const int point = pt0 + row;
        const int batch = point / PPTS;
        const float* xp = xin + point * 3;
        const float* cp = cond + batch * 48;
#pragma unroll
        for (int h = 0; h < 2; ++h) {
            bf16x8 v;
#pragma unroll
            for (int i = 0; i < 8; ++i) {
                int c = c0 + h * 8 + i;
                float f = (c < 3) ? xp[c] : ((c < 51) ? cp[c - 3] : 0.0f);
                v[i] = f2bf(f);
            }
            *(bf16x8*)xaddr(xb, row, c0 + h * 8) = v;
        }
    }
    bar_lgkm();

    layer_fwd<2, 0>(xb, W +     0, W +  2048, b0, lane, wid, apre); bar_lgkm();
    layer_fwd<8, 0>(xb, W +  2048, W + 10240, b1, lane, wid, apre); bar_lgkm();
    layer_fwd<8, 0>(xb, W + 10240, W + 18432, b2, lane, wid, apre); bar_lgkm();
    layer_fwd<8, 1>(xb, W + 18432, W + 26624, b3, lane, wid, apre);
    // skip-write in the SAME write window as layer 3's epilogue (cols 253..255
    // are written by no one else; reads of them finished before L3's internal bar)
    if (t < 64) {
#pragma unroll
        for (int c = 0; c < 3; ++c)
            *xaddr(xb, t, 253 + c) = f2bf(sk[c]);
    }
    bar_lgkm();
    layer_fwd<8, 0>(xb, W + 26624, W + 34816, b4, lane, wid, apre); bar_lgkm();
    layer_fwd<8, 0>(xb, W + 34816, W + 43008, b5, lane, wid, apre); bar_lgkm();
    layer_fwd<8, 0>(xb, W + 43008, W + 51200, b6, lane, wid, apre); bar_lgkm();
    layer_fwd<8, 0>(xb, W + 51200, W + 59392, b7, lane, wid, apre); bar_lgkm();

    // layer 8: N=257 (17 n-tiles), no activation, bias in acc-init, f32 store.
    // Two m-halves to keep live accumulators small; apre feeds half 0, ks 0.
    {
        const bf16x8* wl = W + 59392;
        const int prow = lane & 15;
        const int kg   = (lane >> 4) << 3;
        const int rb4  = (lane >> 4) << 2;
        const float blast = b8[256];
#pragma unroll
        for (int half = 0; half < 2; ++half) {
            f32x4 acc[2][4];
            f32x4 acc2[2];
#pragma unroll
            for (int nii = 0; nii < 4; ++nii) {
                const int cb = (wid * 4 + nii) * 16 + rb4;          // <= 252
                const f32x4 bv = *(const f32x4*)(b8 + cb);
#pragma unroll
                for (int m2 = 0; m2 < 2; ++m2)
                    acc[m2][nii] = bv;
            }
            {
                f32x4 bz = {(rb4 == 0) ? blast : 0.f, 0.f, 0.f, 0.f};
                acc2[0] = bz; acc2[1] = bz;
            }
#pragma unroll 2
            for (int ks = 0; ks < 8; ++ks) {
                bf16x8 a[4], b[2], a2;
#pragma unroll
                for (int nii = 0; nii < 4; ++nii)
                    a[nii] = (half == 0 && ks == 0) ? apre[nii]
                             : wl[((wid * 4 + nii) * 8 + ks) * 64 + lane];
                if (wid == 0) a2 = wl[(128 + ks) * 64 + lane];
#pragma unroll
                for (int m2 = 0; m2 < 2; ++m2)
                    b[m2] = *(const bf16x8*)xaddrc(xb, (half * 2 + m2) * 16 + prow,
                                                   ks * 32 + kg);
#pragma unroll
                for (int m2 = 0; m2 < 2; ++m2)
#pragma unroll
                    for (int nii = 0; nii < 4; ++nii)
                        acc[m2][nii] = __builtin_amdgcn_mfma_f32_16x16x32_bf16(
                            a[nii], b[m2], acc[m2][nii], 0, 0, 0);
                if (wid == 0) {
#pragma unroll
                    for (int m2 = 0; m2 < 2; ++m2)
                        acc2[m2] = __builtin_amdgcn_mfma_f32_16x16x32_bf16(
                            a2, b[m2], acc2[m2], 0, 0, 0);
                }
            }
#pragma unroll
            for (int nii = 0; nii < 4; ++nii) {
                const int cb = (wid * 4 + nii) * 16 + rb4;          // <= 252
#pragma unroll
                for (int m2 = 0; m2 < 2; ++m2) {
                    const int rowoff = (pt0 + (half * 2 + m2) * 16 + prow) * 257 + cb;
#pragma unroll
                    for (int r = 0; r < 4; ++r)
                        out[rowoff + r] = acc[m2][nii][r];
                }
            }
            if (wid == 0 && rb4 == 0) {                              // lanes 0..15
#pragma unroll
                for (int m2 = 0; m2 < 2; ++m2)
                    out[(pt0 + (half * 2 + m2) * 16 + prow) * 257 + 256]
                        = acc2[m2][0];
            }
        }
    }
}

extern "C" void kernel_launch(void* const* d_in, const int* in_sizes, int n_in,
                              void* d_out, int out_size, void* d_ws, size_t ws_size,
                              hipStream_t stream)
{
    const float* xin  = (const float*)d_in[0];
    const float* cond = (const float*)d_in[1];
    const float* Wp[9]; const float* bp[9];
    for (int l = 0; l < 9; ++l) { Wp[l] = (const float*)d_in[2 + 2 * l]; bp[l] = (const float*)d_in[3 + 2 * l]; }
    short* wbf = (short*)d_ws;   // needs 1,089,536 B

    prep_kernel<<<dim3(266), dim3(256), 0, stream>>>(
        Wp[0], Wp[1], Wp[2], Wp[3], Wp[4], Wp[5], Wp[6], Wp[7], Wp[8], wbf);
    net_kernel<<<dim3(3125), dim3(256), 0, stream>>>(
        xin, cond, (const bf16x8*)wbf,
        bp[0], bp[1], bp[2], bp[3], bp[4], bp[5], bp[6], bp[7], bp[8],
        (float*)d_out);
}